// Round 1
// baseline (247.276 us; speedup 1.0000x reference)
//
#include <hip/hip_runtime.h>

typedef unsigned short u16;
typedef __attribute__((ext_vector_type(8))) __bf16 bf16x8;
typedef __attribute__((ext_vector_type(4))) float f32x4;
typedef __attribute__((ext_vector_type(4))) unsigned short u16x4;
typedef __attribute__((ext_vector_type(8))) unsigned short u16x8;

#define AS1 __attribute__((address_space(1)))
#define AS3 __attribute__((address_space(3)))

// blob layout (u16 element offsets) -- bf16 copies of GEMM inputs
#define OB_X    0L
#define OB_H    4194304L
#define OB_WI   8388608L
#define OB_WF   10485760L
#define OB_WO   12582912L
#define OB_WXS  14680064L
#define OB_WXG  15728640L
#define OB_WHG  16777216L
#define BLOB_EL 17825792L

__device__ __forceinline__ u16 f2b(float f) {
    unsigned u = __float_as_uint(f);
    u += 0x7fffu + ((u >> 16) & 1u);   // round-to-nearest-even
    return (u16)(u >> 16);
}

// ---------------- f32 -> bf16 blob build ----------------
__global__ __launch_bounds__(256) void convert_all(
    const float* __restrict__ x, const float* __restrict__ h,
    const float* __restrict__ Wi, const float* __restrict__ Wf,
    const float* __restrict__ Wo, const float* __restrict__ Wxs,
    const float* __restrict__ Wxg, const float* __restrict__ Whg,
    u16* __restrict__ blob)
{
    long e = ((long)blockIdx.x * 256 + threadIdx.x) * 8;
    const float* src; long off;
    if      (e < OB_H)   { src = x;   off = e; }
    else if (e < OB_WI)  { src = h;   off = e - OB_H; }
    else if (e < OB_WF)  { src = Wi;  off = e - OB_WI; }
    else if (e < OB_WO)  { src = Wf;  off = e - OB_WF; }
    else if (e < OB_WXS) { src = Wo;  off = e - OB_WO; }
    else if (e < OB_WXG) { src = Wxs; off = e - OB_WXS; }
    else if (e < OB_WHG) { src = Wxg; off = e - OB_WXG; }
    else                 { src = Whg; off = e - OB_WHG; }
    f32x4 v0 = *(const f32x4*)(src + off);
    f32x4 v1 = *(const f32x4*)(src + off + 4);
    u16x8 o;
    o[0] = f2b(v0.x); o[1] = f2b(v0.y); o[2] = f2b(v0.z); o[3] = f2b(v0.w);
    o[4] = f2b(v1.x); o[5] = f2b(v1.y); o[6] = f2b(v1.z); o[7] = f2b(v1.w);
    *(u16x8*)(blob + e) = o;   // one 16-B store
}

__device__ __forceinline__ float sigf(float z) {
    return 1.f / (1.f + __expf(-z));
}

// Stage one K-step (64-wide) for A (256x64) + 5 B-segs (64x64 each)
// 512 threads: er = t>>3 in [0,64) = row within 64-row chunk, 8 u16/thread.
// XOR-swizzled SOURCE granule (gsw) + linear LDS dest (global_load_lds rule):
// LDS[row][g] holds global granule (g ^ (row&7)) -- read side applies same XOR.
__device__ __forceinline__ void stage_tile(
    u16* As, u16* Bs, int k0,
    const u16* aLo, const u16* aHi,
    const u16* w0, const u16* w1, const u16* w2,
    const u16* w3lo, const u16* w3hi, const u16* w4,
    int t, int er, int gsw)
{
    const u16* aSrc = ((k0 < 1024) ? aLo : aHi) + (k0 & 1023) + gsw;
#pragma unroll
    for (int it = 0; it < 4; ++it) {
        __builtin_amdgcn_global_load_lds(
            (AS1 void*)(aSrc + (it * 64 + er) * 1024),
            (AS3 void*)(As + (it * 512 + t) * 8), 16, 0, 0);
    }
    __builtin_amdgcn_global_load_lds((AS1 void*)(w0 + k0 + er * 2048 + gsw),
        (AS3 void*)(Bs + t * 8), 16, 0, 0);
    __builtin_amdgcn_global_load_lds((AS1 void*)(w1 + k0 + er * 2048 + gsw),
        (AS3 void*)(Bs + 4096 + t * 8), 16, 0, 0);
    __builtin_amdgcn_global_load_lds((AS1 void*)(w2 + k0 + er * 2048 + gsw),
        (AS3 void*)(Bs + 8192 + t * 8), 16, 0, 0);
    const u16* w3 = (k0 < 1024) ? (w3lo + k0) : (w3hi + (k0 - 1024));
    __builtin_amdgcn_global_load_lds((AS1 void*)(w3 + er * 1024 + gsw),
        (AS3 void*)(Bs + 12288 + t * 8), 16, 0, 0);
    if (k0 < 1024)
        __builtin_amdgcn_global_load_lds((AS1 void*)(w4 + k0 + er * 1024 + gsw),
            (AS3 void*)(Bs + 16384 + t * 8), 16, 0, 0);
}

// MFMA over one staged K-step from LDS buffers (verified fragment mapping)
__device__ __forceinline__ void compute_tile(
    const u16* As, const u16* Bs, bool seg4,
    int wm, int wn, int fr, int fq, int r7,
    f32x4 (&acc)[5][4][2])
{
#pragma unroll
    for (int kk = 0; kk < 64; kk += 32) {
        const int sw = ((((kk >> 3) + fq) ^ r7) << 3);
        bf16x8 a[4];
#pragma unroll
        for (int mi = 0; mi < 4; ++mi)
            a[mi] = *(const bf16x8*)(As + (wm + mi * 16 + fr) * 64 + sw);
#pragma unroll
        for (int s = 0; s < 4; ++s) {
            bf16x8 b0 = *(const bf16x8*)(Bs + s * 4096 + (wn + fr) * 64 + sw);
            bf16x8 b1 = *(const bf16x8*)(Bs + s * 4096 + (wn + 16 + fr) * 64 + sw);
#pragma unroll
            for (int mi = 0; mi < 4; ++mi) {
                acc[s][mi][0] = __builtin_amdgcn_mfma_f32_16x16x32_bf16(
                    a[mi], b0, acc[s][mi][0], 0, 0, 0);
                acc[s][mi][1] = __builtin_amdgcn_mfma_f32_16x16x32_bf16(
                    a[mi], b1, acc[s][mi][1], 0, 0, 0);
            }
        }
        if (seg4) {                    // seg 4 (Wxs) has K=1024
            bf16x8 b0 = *(const bf16x8*)(Bs + 16384 + (wn + fr) * 64 + sw);
            bf16x8 b1 = *(const bf16x8*)(Bs + 16384 + (wn + 16 + fr) * 64 + sw);
#pragma unroll
            for (int mi = 0; mi < 4; ++mi) {
                acc[4][mi][0] = __builtin_amdgcn_mfma_f32_16x16x32_bf16(
                    a[mi], b0, acc[4][mi][0], 0, 0, 0);
                acc[4][mi][1] = __builtin_amdgcn_mfma_f32_16x16x32_bf16(
                    a[mi], b1, acc[4][mi][1], 0, 0, 0);
            }
        }
    }
}

// ---------------- fully-fused SRU-LSTM cell, double-buffered 2-phase ----------------
// Block = 512 threads (8 waves, 4m x 2n), tile 256m x 64j x 5 segs, BK=64.
// Grid 16x16 = 256 blocks = 1 block/CU (144 KB LDS), 2 waves/SIMD.
// Pipeline: issue STAGE(next buf) -> compute(cur buf) -> barrier (drains vmcnt),
// so global->LDS latency hides under ~72 MFMAs instead of being fully exposed
// (the old single-buffer structure drained vmcnt(0) BEFORE every compute phase).
__global__ __launch_bounds__(512, 2) void srulstm_fused(
    const u16* __restrict__ blob,
    const float* __restrict__ c_prev,
    const float* __restrict__ bi, const float* __restrict__ bfv,
    const float* __restrict__ bo, const float* __restrict__ bxs,
    const float* __restrict__ bxg, const float* __restrict__ bhg,
    float* __restrict__ out)
{
    __shared__ __align__(16) u16 As[2][256 * 64];       // 2 x 32 KB
    __shared__ __align__(16) u16 Bs[2][5 * 64 * 64];    // 2 x 40 KB

    const u16* x = blob + OB_X;
    const u16* h = blob + OB_H;

    const int t = threadIdx.x;
    const int j0 = blockIdx.x * 64;    // 16 j-slices
    const int m0 = blockIdx.y * 256;   // 16 m-tiles

    const u16* w0   = blob + OB_WI  + j0 * 2048;
    const u16* w1   = blob + OB_WF  + j0 * 2048;
    const u16* w2   = blob + OB_WO  + j0 * 2048;
    const u16* w3lo = blob + OB_WXG + j0 * 1024;
    const u16* w3hi = blob + OB_WHG + j0 * 1024;
    const u16* w4   = blob + OB_WXS + j0 * 1024;

    const u16* aLo = x + m0 * 1024;
    const u16* aHi = h + m0 * 1024;

    const int lane = t & 63;
    const int wave = t >> 6;           // 0..7
    const int wm = (wave >> 1) << 6;   // 0/64/128/192
    const int wn = (wave & 1) << 5;    // 0/32
    const int fr = lane & 15;
    const int fq = lane >> 4;
    const int r7 = fr & 7;

    const int er = t >> 3;             // staging row in 64-row chunk (0..63)
    const int gsw = (((t & 7) ^ (er & 7)) << 3);

    f32x4 acc[5][4][2] = {};           // [seg][mi][ni]

    // prologue: fill buffer 0
    stage_tile(As[0], Bs[0], 0, aLo, aHi, w0, w1, w2, w3lo, w3hi, w4, t, er, gsw);
    __syncthreads();                   // implies vmcnt(0) drain

    for (int k0 = 0; k0 < 2048; k0 += 128) {
        // phase A: prefetch k0+64 into buf1 while computing buf0
        stage_tile(As[1], Bs[1], k0 + 64,
                   aLo, aHi, w0, w1, w2, w3lo, w3hi, w4, t, er, gsw);
        compute_tile(As[0], Bs[0], k0 < 1024, wm, wn, fr, fq, r7, acc);
        __syncthreads();
        // phase B: prefetch k0+128 into buf0 while computing buf1
        if (k0 + 128 < 2048)
            stage_tile(As[0], Bs[0], k0 + 128,
                       aLo, aHi, w0, w1, w2, w3lo, w3hi, w4, t, er, gsw);
        compute_tile(As[1], Bs[1], (k0 + 64) < 1024, wm, wn, fr, fq, r7, acc);
        __syncthreads();
    }

    // ---- in-register LSTM epilogue ----
    // C/D layout (m89): lane holds D[m=fq*4+r][n=fr]; all 5 segs aligned.
    const int orow = m0 + wm + (fq << 2);
    const int ocol = j0 + wn + fr;
#pragma unroll
    for (int ni = 0; ni < 2; ++ni) {
        const int col = ocol + ni * 16;
        const float bi_v = bi[col],  bf_v = bfv[col], bo_v = bo[col];
        const float bs_v = bxs[col], bg_v = bxg[col], bh_v = bhg[col];
#pragma unroll
        for (int mi = 0; mi < 4; ++mi) {
#pragma unroll
            for (int r = 0; r < 4; ++r) {
                const long idx = (long)(orow + mi * 16 + r) * 1024 + col;
                const float cp = c_prev[idx];
                const float i_t = sigf(acc[0][mi][ni][r] + bi_v);
                const float f_t = sigf(acc[1][mi][ni][r] + bf_v);
                const float o_t = sigf(acc[2][mi][ni][r] + bo_v);
                const float cand = acc[3][mi][ni][r] + bg_v + bh_v;
                const float s_t  = acc[4][mi][ni][r] + bs_v;
                const float g_t = tanhf(s_t * cand);
                const float c_t = f_t * cp + i_t * g_t;
                const float h_t = o_t * tanhf(c_t);
                out[idx] = h_t;                    // h_t
                out[4194304L + idx] = c_t;         // c_t
            }
        }
    }
}

extern "C" void kernel_launch(void* const* d_in, const int* in_sizes, int n_in,
                              void* d_out, int out_size, void* d_ws, size_t ws_size,
                              hipStream_t stream)
{
    u16* blob = (u16*)d_ws;            // 35.7 MB
    float* out = (float*)d_out;

    const long convBlocks = BLOB_EL / 8 / 256;     // 8704

    convert_all<<<dim3(convBlocks), dim3(256), 0, stream>>>(
        (const float*)d_in[0], (const float*)d_in[1], (const float*)d_in[3],
        (const float*)d_in[5], (const float*)d_in[7], (const float*)d_in[9],
        (const float*)d_in[11], (const float*)d_in[13], blob);

    srulstm_fused<<<dim3(16, 16), dim3(512), 0, stream>>>(
        blob, (const float*)d_in[2], (const float*)d_in[4], (const float*)d_in[6],
        (const float*)d_in[8], (const float*)d_in[10], (const float*)d_in[12],
        (const float*)d_in[14], out);
}